// Round 5
// baseline (297.518 us; speedup 1.0000x reference)
//
#include <hip/hip_runtime.h>
#include <hip/hip_bf16.h>

#define N_NODES 100000
#define N_EDGES 600000
#define D 128
#define ROWS_PB 32                               // dst rows per fused block
#define NBLK_F (N_NODES / ROWS_PB)               // 3125
#define CAPN 32                                  // per-node bucket capacity (mean deg 6, P(>31)~7e-14)
#define GSTR 132                                 // padded LDS row stride (floats)

typedef __attribute__((ext_vector_type(8))) short short8;
typedef __attribute__((ext_vector_type(8))) unsigned short ushort8;
typedef __attribute__((ext_vector_type(4))) float f32x4;
typedef __attribute__((ext_vector_type(2))) int i32x2;
typedef __attribute__((ext_vector_type(2))) float f32x2;

union V8 { short8 s8; ushort8 u8; };

__device__ __forceinline__ unsigned short f2bf(float f) {
    unsigned u = __float_as_uint(f);
    u += 0x7FFF + ((u >> 16) & 1);   // RNE
    return (unsigned short)(u >> 16);
}

// ---------------- weight fragments + per-node cursor zeroing ----------------
// grid = 64 blocks (16384 threads): all clear cur; first 4096 build W frags.
__global__ void wfrag_kernel(const float* __restrict__ Wi,
                             const float* __restrict__ We,
                             unsigned short* __restrict__ Wfi,
                             unsigned short* __restrict__ Wfe,
                             unsigned* __restrict__ cur) {
    int id = blockIdx.x * blockDim.x + threadIdx.x;   // 0..16383
    for (int j = id; j < N_NODES; j += 16384) cur[j] = 0u;   // fold memset in
    if (id >= 4096) return;
    int mat = id >> 11;
    int idx = id & 2047;          // nt<<8 | ks<<6 | lane
    int lane = idx & 63;
    int ks = (idx >> 6) & 3;
    int nt = idx >> 8;
    int n = lane & 15, quad = lane >> 4;
    int row = nt * 16 + n;
    int k0 = ks * 32 + quad * 8;
    const float* W = mat ? We : Wi;
    unsigned short* Wf = mat ? Wfe : Wfi;
    #pragma unroll
    for (int j = 0; j < 8; ++j)
        Wf[idx * 8 + j] = f2bf(W[row * D + k0 + j]);
}

// ---------------- one-pass per-node bucket scatter ----------------
// 2 edges/thread, vector loads, nontemporal (streamed-once) accesses.
// bucket d holds its edges' {src, ew} pairs; within-bucket order irrelevant.
__global__ void scatter_kernel(const i32x2* __restrict__ src2,
                               const i32x2* __restrict__ dst2,
                               const f32x2* __restrict__ ew2,
                               unsigned* __restrict__ cur,
                               i32x2* __restrict__ bkt) {
    int i = blockIdx.x * blockDim.x + threadIdx.x;
    if (i < N_EDGES / 2) {
        i32x2 s = __builtin_nontemporal_load(&src2[i]);
        i32x2 d = __builtin_nontemporal_load(&dst2[i]);
        f32x2 wv = __builtin_nontemporal_load(&ew2[i]);
        unsigned p0 = atomicAdd(&cur[d[0]], 1u);
        unsigned p1 = atomicAdd(&cur[d[1]], 1u);
        if (p0 < CAPN) {
            i32x2 m = {s[0], __float_as_int(wv[0])};
            __builtin_nontemporal_store(m, &bkt[(size_t)d[0] * CAPN + p0]);
        }
        if (p1 < CAPN) {
            i32x2 m = {s[1], __float_as_int(wv[1])};
            __builtin_nontemporal_store(m, &bkt[(size_t)d[1] * CAPN + p1]);
        }
    }
}

// ---------------- fused gather-sum + dual GEMM + leaky ----------------
// out = leaky( (dst_x + g) @ Wi^T + (dst_x .* g) @ We^T ),
// g[d] = sum_{e: dst=d} ew_e * src_x[src_e]  (exact f32).
// Gather: each quad (16 lanes) owns 2 whole dst nodes; accumulates each
// node's g-row in registers (no atomics, no sort), 1-deep row prefetch,
// then ONE plain float4 LDS store per row half.
// MFMA phase: W fragments loaded after gather; two 16-row tiles; leaky
// fused; out stored exactly once. (Structure verified round 4.)
// launch_bounds (256, 8): VGPR 44 / LDS 16.9KB allow 8 blocks/CU; round-4's
// (256,4) capped occupancy at 44% on a latency-bound gather.
__global__ __launch_bounds__(256, 8) void fused_kernel(
    const float* __restrict__ src_x,
    const float* __restrict__ dst_x,
    const int2* __restrict__ bkt,
    const unsigned* __restrict__ cur,
    const unsigned short* __restrict__ Wfi,
    const unsigned short* __restrict__ Wfe,
    float* __restrict__ out) {
    __shared__ float g[ROWS_PB * GSTR];   // 32 x 132 f32 = 16.9 KB

    int t = threadIdx.x, lane = t & 63, w = t >> 6;
    int quad = lane >> 4, nl = lane & 15;
    int qid = t >> 4;                      // 0..15

    int b = blockIdx.x, d0 = b * ROWS_PB;

    // ---- gather: quad qid owns local rows 2*qid and 2*qid+1 ----
    #pragma unroll
    for (int half = 0; half < 2; ++half) {
        int r = 2 * qid + half;            // local row 0..31
        int node = d0 + r;
        int cn = (int)cur[node];
        if (cn > CAPN) cn = CAPN;
        const int2* bp = bkt + (size_t)node * CAPN;
        float4 a = {0.f, 0.f, 0.f, 0.f}, c = {0.f, 0.f, 0.f, 0.f};
        if (cn > 0) {
            int2 m0 = bp[0];
            const float* p0 = src_x + (size_t)m0.x * D + nl * 8;
            float4 A0 = *(const float4*)p0, B0 = *(const float4*)(p0 + 4);
            for (int e = 0; e < cn; ++e) {
                int en = (e + 1 < cn) ? e + 1 : cn - 1;
                int2 m1 = bp[en];
                const float* p1 = src_x + (size_t)m1.x * D + nl * 8;
                float4 A1 = *(const float4*)p1, B1 = *(const float4*)(p1 + 4);
                float wgt = __int_as_float(m0.y);
                a.x += wgt * A0.x; a.y += wgt * A0.y;
                a.z += wgt * A0.z; a.w += wgt * A0.w;
                c.x += wgt * B0.x; c.y += wgt * B0.y;
                c.z += wgt * B0.z; c.w += wgt * B0.w;
                m0 = m1; A0 = A1; B0 = B1;
            }
        }
        float* gp = &g[r * GSTR + nl * 8];
        *(float4*)gp = a;                  // plain stores: quad owns the row
        *(float4*)(gp + 4) = c;
    }
    __syncthreads();

    // ---- MFMA phase: W fragments (compiler sinks loads here) ----
    const short8* Wiv = (const short8*)Wfi;
    const short8* Wev = (const short8*)Wfe;
    short8 Bi[2][4], Be[2][4];
    #pragma unroll
    for (int ntl = 0; ntl < 2; ++ntl)
        #pragma unroll
        for (int ks = 0; ks < 4; ++ks) {
            Bi[ntl][ks] = Wiv[((2 * w + ntl) * 4 + ks) * 64 + lane];
            Be[ntl][ks] = Wev[((2 * w + ntl) * 4 + ks) * 64 + lane];
        }

    #pragma unroll
    for (int tl = 0; tl < 2; ++tl) {
        int r = tl * 16 + nl;                        // local row 0..31
        const float* xr = dst_x + (size_t)(d0 + r) * D + quad * 8;
        const float* gr = &g[r * GSTR + quad * 8];
        f32x4 acc[2];
        acc[0] = (f32x4){0.f, 0.f, 0.f, 0.f};
        acc[1] = (f32x4){0.f, 0.f, 0.f, 0.f};
        #pragma unroll
        for (int ks = 0; ks < 4; ++ks) {
            float4 f0 = *(const float4*)(xr + ks * 32);
            float4 f1 = *(const float4*)(xr + ks * 32 + 4);
            float4 g0 = *(const float4*)(gr + ks * 32);
            float4 g1 = *(const float4*)(gr + ks * 32 + 4);
            V8 a1v, a2v;
            a1v.u8[0] = f2bf(f0.x + g0.x); a2v.u8[0] = f2bf(f0.x * g0.x);
            a1v.u8[1] = f2bf(f0.y + g0.y); a2v.u8[1] = f2bf(f0.y * g0.y);
            a1v.u8[2] = f2bf(f0.z + g0.z); a2v.u8[2] = f2bf(f0.z * g0.z);
            a1v.u8[3] = f2bf(f0.w + g0.w); a2v.u8[3] = f2bf(f0.w * g0.w);
            a1v.u8[4] = f2bf(f1.x + g1.x); a2v.u8[4] = f2bf(f1.x * g1.x);
            a1v.u8[5] = f2bf(f1.y + g1.y); a2v.u8[5] = f2bf(f1.y * g1.y);
            a1v.u8[6] = f2bf(f1.z + g1.z); a2v.u8[6] = f2bf(f1.z * g1.z);
            a1v.u8[7] = f2bf(f1.w + g1.w); a2v.u8[7] = f2bf(f1.w * g1.w);
            acc[0] = __builtin_amdgcn_mfma_f32_16x16x32_bf16(a1v.s8, Bi[0][ks], acc[0], 0, 0, 0);
            acc[1] = __builtin_amdgcn_mfma_f32_16x16x32_bf16(a1v.s8, Bi[1][ks], acc[1], 0, 0, 0);
            acc[0] = __builtin_amdgcn_mfma_f32_16x16x32_bf16(a2v.s8, Be[0][ks], acc[0], 0, 0, 0);
            acc[1] = __builtin_amdgcn_mfma_f32_16x16x32_bf16(a2v.s8, Be[1][ks], acc[1], 0, 0, 0);
        }
        // store with fused leaky; C layout as verified
        #pragma unroll
        for (int ntl = 0; ntl < 2; ++ntl)
            #pragma unroll
            for (int rr = 0; rr < 4; ++rr) {
                float v = acc[ntl][rr];
                v = v > 0.f ? v : 0.01f * v;
                out[(size_t)(d0 + tl * 16 + quad * 4 + rr) * D
                    + (2 * w + ntl) * 16 + nl] = v;
            }
    }
}

extern "C" void kernel_launch(void* const* d_in, const int* in_sizes, int n_in,
                              void* d_out, int out_size, void* d_ws, size_t ws_size,
                              hipStream_t stream) {
    const float* src_x = (const float*)d_in[0];
    const float* dst_x = (const float*)d_in[1];
    const int*   eidx  = (const int*)d_in[2];     // [2, E] flat: src then dst
    const float* ew    = (const float*)d_in[3];   // [E, 1]
    const float* Wi    = (const float*)d_in[4];   // [D, D]
    const float* We    = (const float*)d_in[5];   // [D, D]
    float* out = (float*)d_out;

    // ws layout
    char* wsb = (char*)d_ws;
    unsigned short* Wfi = (unsigned short*)(wsb);            // 32768 B
    unsigned short* Wfe = (unsigned short*)(wsb + 32768);    // 32768 B
    unsigned* cur = (unsigned*)(wsb + 65536);                // 400000 B
    int2* bkt = (int2*)(wsb + 65536 + 400000);               // 100000*32*8 = 25.6 MB

    const int* src_idx = eidx;
    const int* dst_idx = eidx + N_EDGES;

    wfrag_kernel<<<64, 256, 0, stream>>>(Wi, We, Wfi, Wfe, cur);

    scatter_kernel<<<(N_EDGES / 2 + 255) / 256, 256, 0, stream>>>(
        (const i32x2*)src_idx, (const i32x2*)dst_idx, (const f32x2*)ew,
        cur, (i32x2*)bkt);

    fused_kernel<<<NBLK_F, 256, 0, stream>>>(
        src_x, dst_x, (const int2*)bkt, cur, Wfi, Wfe, out);
}

// Round 7
// 293.504 us; speedup vs baseline: 1.0137x; 1.0137x over previous
//
#include <hip/hip_runtime.h>
#include <hip/hip_bf16.h>

#define N_NODES 100000
#define N_EDGES 600000
#define D 128
#define ROWS_PB 32                               // dst rows per fused block
#define NBLK_F (N_NODES / ROWS_PB)               // 3125
#define CAPN 32                                  // per-node bucket capacity (mean deg 6, P(>31)~7e-14)
#define GSTR 132                                 // padded LDS row stride (floats)

typedef __attribute__((ext_vector_type(8))) short short8;
typedef __attribute__((ext_vector_type(8))) unsigned short ushort8;
typedef __attribute__((ext_vector_type(4))) float f32x4;
typedef __attribute__((ext_vector_type(2))) int i32x2;
typedef __attribute__((ext_vector_type(2))) float f32x2;

union V8 { short8 s8; ushort8 u8; };

__device__ __forceinline__ unsigned short f2bf(float f) {
    unsigned u = __float_as_uint(f);
    u += 0x7FFF + ((u >> 16) & 1);   // RNE
    return (unsigned short)(u >> 16);
}

// ---------------- weight fragments + per-node cursor zeroing ----------------
// grid = 64 blocks (16384 threads): all clear cur; first 4096 build W frags.
__global__ void wfrag_kernel(const float* __restrict__ Wi,
                             const float* __restrict__ We,
                             unsigned short* __restrict__ Wfi,
                             unsigned short* __restrict__ Wfe,
                             unsigned* __restrict__ cur) {
    int id = blockIdx.x * blockDim.x + threadIdx.x;   // 0..16383
    for (int j = id; j < N_NODES; j += 16384) cur[j] = 0u;   // fold memset in
    if (id >= 4096) return;
    int mat = id >> 11;
    int idx = id & 2047;          // nt<<8 | ks<<6 | lane
    int lane = idx & 63;
    int ks = (idx >> 6) & 3;
    int nt = idx >> 8;
    int n = lane & 15, quad = lane >> 4;
    int row = nt * 16 + n;
    int k0 = ks * 32 + quad * 8;
    const float* W = mat ? We : Wi;
    unsigned short* Wf = mat ? Wfe : Wfi;
    #pragma unroll
    for (int j = 0; j < 8; ++j)
        Wf[idx * 8 + j] = f2bf(W[row * D + k0 + j]);
}

// ---------------- one-pass per-node bucket scatter ----------------
// 2 edges/thread, vector loads, nontemporal (streamed-once) accesses.
// bucket d holds its edges' {src, ew} pairs; within-bucket order irrelevant.
__global__ void scatter_kernel(const i32x2* __restrict__ src2,
                               const i32x2* __restrict__ dst2,
                               const f32x2* __restrict__ ew2,
                               unsigned* __restrict__ cur,
                               i32x2* __restrict__ bkt) {
    int i = blockIdx.x * blockDim.x + threadIdx.x;
    if (i < N_EDGES / 2) {
        i32x2 s = __builtin_nontemporal_load(&src2[i]);
        i32x2 d = __builtin_nontemporal_load(&dst2[i]);
        f32x2 wv = __builtin_nontemporal_load(&ew2[i]);
        unsigned p0 = atomicAdd(&cur[d[0]], 1u);
        unsigned p1 = atomicAdd(&cur[d[1]], 1u);
        if (p0 < CAPN) {
            i32x2 m = {s[0], __float_as_int(wv[0])};
            __builtin_nontemporal_store(m, &bkt[(size_t)d[0] * CAPN + p0]);
        }
        if (p1 < CAPN) {
            i32x2 m = {s[1], __float_as_int(wv[1])};
            __builtin_nontemporal_store(m, &bkt[(size_t)d[1] * CAPN + p1]);
        }
    }
}

// ---------------- fused gather-sum + dual GEMM + leaky ----------------
// out = leaky( (dst_x + g) @ Wi^T + (dst_x .* g) @ We^T ),
// g[d] = sum_{e: dst=d} ew_e * src_x[src_e]  (exact f32).
// Gather: each quad (16 lanes) owns 2 whole dst nodes. The two per-node
// accumulation chains are INTERLEAVED in one loop (independent 1-deep
// prefetch each) for 2x memory-level parallelism per wave; consumption is
// predicated on e<cnK. No atomics, no sort; one plain float4 LDS store
// per row half at the end.
// launch_bounds (256,6): 6 blocks/CU (LDS 101KB, 24 waves) with VGPR
// budget ~85 -- enough for the dual-chain pipeline WITHOUT spilling.
// Round-5 lesson: (256,8) compressed to 32 VGPR -> 161MB spill traffic.
__global__ __launch_bounds__(256, 6) void fused_kernel(
    const float* __restrict__ src_x,
    const float* __restrict__ dst_x,
    const int2* __restrict__ bkt,
    const unsigned* __restrict__ cur,
    const unsigned short* __restrict__ Wfi,
    const unsigned short* __restrict__ Wfe,
    float* __restrict__ out) {
    __shared__ float g[ROWS_PB * GSTR];   // 32 x 132 f32 = 16.9 KB

    int t = threadIdx.x, lane = t & 63, w = t >> 6;
    int quad = lane >> 4, nl = lane & 15;
    int qid = t >> 4;                      // 0..15

    int b = blockIdx.x, d0 = b * ROWS_PB;

    // ---- gather: quad qid owns local rows 2*qid and 2*qid+1, interleaved ----
    int r0 = 2 * qid, r1 = 2 * qid + 1;
    uint2 cn2 = *(const uint2*)&cur[d0 + r0];   // consecutive, 8B-aligned
    int cn0 = (int)cn2.x; if (cn0 > CAPN) cn0 = CAPN;
    int cn1 = (int)cn2.y; if (cn1 > CAPN) cn1 = CAPN;
    const int2* bp0 = bkt + (size_t)(d0 + r0) * CAPN;
    const int2* bp1 = bkt + (size_t)(d0 + r1) * CAPN;

    float4 a0 = {0.f,0.f,0.f,0.f}, c0 = {0.f,0.f,0.f,0.f};
    float4 a1 = {0.f,0.f,0.f,0.f}, c1 = {0.f,0.f,0.f,0.f};

    // chain state (zero-init so no undef flows through masked lanes)
    int2 m0 = make_int2(0,0), m0n = make_int2(0,0);
    int2 m1 = make_int2(0,0), m1n = make_int2(0,0);
    float4 A0 = {0,0,0,0}, B0 = {0,0,0,0}, A0n = {0,0,0,0}, B0n = {0,0,0,0};
    float4 A1 = {0,0,0,0}, B1 = {0,0,0,0}, A1n = {0,0,0,0}, B1n = {0,0,0,0};

    if (cn0 > 0) {
        m0 = bp0[0];
        const float* p = src_x + (size_t)m0.x * D + nl * 8;
        A0 = *(const float4*)p; B0 = *(const float4*)(p + 4);
        m0n = bp0[cn0 > 1 ? 1 : 0];
        const float* pn = src_x + (size_t)m0n.x * D + nl * 8;
        A0n = *(const float4*)pn; B0n = *(const float4*)(pn + 4);
    }
    if (cn1 > 0) {
        m1 = bp1[0];
        const float* p = src_x + (size_t)m1.x * D + nl * 8;
        A1 = *(const float4*)p; B1 = *(const float4*)(p + 4);
        m1n = bp1[cn1 > 1 ? 1 : 0];
        const float* pn = src_x + (size_t)m1n.x * D + nl * 8;
        A1n = *(const float4*)pn; B1n = *(const float4*)(pn + 4);
    }

    int maxcn = cn0 > cn1 ? cn0 : cn1;
    for (int e = 0; e < maxcn; ++e) {
        if (e < cn0) {
            float wgt = __int_as_float(m0.y);
            a0.x += wgt * A0.x; a0.y += wgt * A0.y;
            a0.z += wgt * A0.z; a0.w += wgt * A0.w;
            c0.x += wgt * B0.x; c0.y += wgt * B0.y;
            c0.z += wgt * B0.z; c0.w += wgt * B0.w;
            m0 = m0n; A0 = A0n; B0 = B0n;
            int in = e + 2 < cn0 ? e + 2 : cn0 - 1;
            m0n = bp0[in];
            const float* pn = src_x + (size_t)m0n.x * D + nl * 8;
            A0n = *(const float4*)pn; B0n = *(const float4*)(pn + 4);
        }
        if (e < cn1) {
            float wgt = __int_as_float(m1.y);
            a1.x += wgt * A1.x; a1.y += wgt * A1.y;
            a1.z += wgt * A1.z; a1.w += wgt * A1.w;
            c1.x += wgt * B1.x; c1.y += wgt * B1.y;
            c1.z += wgt * B1.z; c1.w += wgt * B1.w;
            m1 = m1n; A1 = A1n; B1 = B1n;
            int in = e + 2 < cn1 ? e + 2 : cn1 - 1;
            m1n = bp1[in];
            const float* pn = src_x + (size_t)m1n.x * D + nl * 8;
            A1n = *(const float4*)pn; B1n = *(const float4*)(pn + 4);
        }
    }

    {   // plain stores: quad owns both rows
        float* gp0 = &g[r0 * GSTR + nl * 8];
        *(float4*)gp0 = a0; *(float4*)(gp0 + 4) = c0;
        float* gp1 = &g[r1 * GSTR + nl * 8];
        *(float4*)gp1 = a1; *(float4*)(gp1 + 4) = c1;
    }
    __syncthreads();

    // ---- MFMA phase: W fragments (compiler sinks loads here) ----
    const short8* Wiv = (const short8*)Wfi;
    const short8* Wev = (const short8*)Wfe;
    short8 Bi[2][4], Be[2][4];
    #pragma unroll
    for (int ntl = 0; ntl < 2; ++ntl)
        #pragma unroll
        for (int ks = 0; ks < 4; ++ks) {
            Bi[ntl][ks] = Wiv[((2 * w + ntl) * 4 + ks) * 64 + lane];
            Be[ntl][ks] = Wev[((2 * w + ntl) * 4 + ks) * 64 + lane];
        }

    #pragma unroll
    for (int tl = 0; tl < 2; ++tl) {
        int r = tl * 16 + nl;                        // local row 0..31
        const float* xr = dst_x + (size_t)(d0 + r) * D + quad * 8;
        const float* gr = &g[r * GSTR + quad * 8];
        f32x4 acc[2];
        acc[0] = (f32x4){0.f, 0.f, 0.f, 0.f};
        acc[1] = (f32x4){0.f, 0.f, 0.f, 0.f};
        #pragma unroll
        for (int ks = 0; ks < 4; ++ks) {
            float4 f0 = *(const float4*)(xr + ks * 32);
            float4 f1 = *(const float4*)(xr + ks * 32 + 4);
            float4 g0 = *(const float4*)(gr + ks * 32);
            float4 g1 = *(const float4*)(gr + ks * 32 + 4);
            V8 a1v, a2v;
            a1v.u8[0] = f2bf(f0.x + g0.x); a2v.u8[0] = f2bf(f0.x * g0.x);
            a1v.u8[1] = f2bf(f0.y + g0.y); a2v.u8[1] = f2bf(f0.y * g0.y);
            a1v.u8[2] = f2bf(f0.z + g0.z); a2v.u8[2] = f2bf(f0.z * g0.z);
            a1v.u8[3] = f2bf(f0.w + g0.w); a2v.u8[3] = f2bf(f0.w * g0.w);
            a1v.u8[4] = f2bf(f1.x + g1.x); a2v.u8[4] = f2bf(f1.x * g1.x);
            a1v.u8[5] = f2bf(f1.y + g1.y); a2v.u8[5] = f2bf(f1.y * g1.y);
            a1v.u8[6] = f2bf(f1.z + g1.z); a2v.u8[6] = f2bf(f1.z * g1.z);
            a1v.u8[7] = f2bf(f1.w + g1.w); a2v.u8[7] = f2bf(f1.w * g1.w);
            acc[0] = __builtin_amdgcn_mfma_f32_16x16x32_bf16(a1v.s8, Bi[0][ks], acc[0], 0, 0, 0);
            acc[1] = __builtin_amdgcn_mfma_f32_16x16x32_bf16(a1v.s8, Bi[1][ks], acc[1], 0, 0, 0);
            acc[0] = __builtin_amdgcn_mfma_f32_16x16x32_bf16(a2v.s8, Be[0][ks], acc[0], 0, 0, 0);
            acc[1] = __builtin_amdgcn_mfma_f32_16x16x32_bf16(a2v.s8, Be[1][ks], acc[1], 0, 0, 0);
        }
        // store with fused leaky; C layout as verified
        #pragma unroll
        for (int ntl = 0; ntl < 2; ++ntl)
            #pragma unroll
            for (int rr = 0; rr < 4; ++rr) {
                float v = acc[ntl][rr];
                v = v > 0.f ? v : 0.01f * v;
                out[(size_t)(d0 + tl * 16 + quad * 4 + rr) * D
                    + (2 * w + ntl) * 16 + nl] = v;
            }
    }
}

extern "C" void kernel_launch(void* const* d_in, const int* in_sizes, int n_in,
                              void* d_out, int out_size, void* d_ws, size_t ws_size,
                              hipStream_t stream) {
    const float* src_x = (const float*)d_in[0];
    const float* dst_x = (const float*)d_in[1];
    const int*   eidx  = (const int*)d_in[2];     // [2, E] flat: src then dst
    const float* ew    = (const float*)d_in[3];   // [E, 1]
    const float* Wi    = (const float*)d_in[4];   // [D, D]
    const float* We    = (const float*)d_in[5];   // [D, D]
    float* out = (float*)d_out;

    // ws layout
    char* wsb = (char*)d_ws;
    unsigned short* Wfi = (unsigned short*)(wsb);            // 32768 B
    unsigned short* Wfe = (unsigned short*)(wsb + 32768);    // 32768 B
    unsigned* cur = (unsigned*)(wsb + 65536);                // 400000 B
    int2* bkt = (int2*)(wsb + 65536 + 400000);               // 100000*32*8 = 25.6 MB

    const int* src_idx = eidx;
    const int* dst_idx = eidx + N_EDGES;

    wfrag_kernel<<<64, 256, 0, stream>>>(Wi, We, Wfi, Wfe, cur);

    scatter_kernel<<<(N_EDGES / 2 + 255) / 256, 256, 0, stream>>>(
        (const i32x2*)src_idx, (const i32x2*)dst_idx, (const f32x2*)ew,
        cur, (i32x2*)bkt);

    fused_kernel<<<NBLK_F, 256, 0, stream>>>(
        src_x, dst_x, (const int2*)bkt, cur, Wfi, Wfe, out);
}

// Round 8
// 276.816 us; speedup vs baseline: 1.0748x; 1.0603x over previous
//
#include <hip/hip_runtime.h>
#include <hip/hip_bf16.h>

#define N_NODES 100000
#define N_EDGES 600000
#define D 128
#define ROWS_PB 32                               // dst rows per fused block
#define NBLK_F (N_NODES / ROWS_PB)               // 3125
#define CAPN 32                                  // per-node bucket capacity (mean deg 6, P(>31)~3e-16)
#define GSTR 132                                 // padded LDS row stride (floats)

typedef __attribute__((ext_vector_type(8))) short short8;
typedef __attribute__((ext_vector_type(8))) unsigned short ushort8;
typedef __attribute__((ext_vector_type(4))) float f32x4;
typedef __attribute__((ext_vector_type(2))) int i32x2;
typedef __attribute__((ext_vector_type(2))) float f32x2;

union V8 { short8 s8; ushort8 u8; };

__device__ __forceinline__ unsigned short f2bf(float f) {
    unsigned u = __float_as_uint(f);
    u += 0x7FFF + ((u >> 16) & 1);   // RNE
    return (unsigned short)(u >> 16);
}

// ---------------- weight fragments + per-node cursor zeroing ----------------
// grid = 64 blocks (16384 threads): all clear cur; first 4096 build W frags.
__global__ void wfrag_kernel(const float* __restrict__ Wi,
                             const float* __restrict__ We,
                             unsigned short* __restrict__ Wfi,
                             unsigned short* __restrict__ Wfe,
                             unsigned* __restrict__ cur) {
    int id = blockIdx.x * blockDim.x + threadIdx.x;   // 0..16383
    for (int j = id; j < N_NODES; j += 16384) cur[j] = 0u;   // fold memset in
    if (id >= 4096) return;
    int mat = id >> 11;
    int idx = id & 2047;          // nt<<8 | ks<<6 | lane
    int lane = idx & 63;
    int ks = (idx >> 6) & 3;
    int nt = idx >> 8;
    int n = lane & 15, quad = lane >> 4;
    int row = nt * 16 + n;
    int k0 = ks * 32 + quad * 8;
    const float* W = mat ? We : Wi;
    unsigned short* Wf = mat ? Wfe : Wfi;
    #pragma unroll
    for (int j = 0; j < 8; ++j)
        Wf[idx * 8 + j] = f2bf(W[row * D + k0 + j]);
}

// ---------------- one-pass per-node bucket scatter ----------------
// 2 edges/thread, vector loads, nontemporal (streamed-once) accesses.
// bucket d holds its edges' {src, ew} pairs; within-bucket order irrelevant.
__global__ void scatter_kernel(const i32x2* __restrict__ src2,
                               const i32x2* __restrict__ dst2,
                               const f32x2* __restrict__ ew2,
                               unsigned* __restrict__ cur,
                               i32x2* __restrict__ bkt) {
    int i = blockIdx.x * blockDim.x + threadIdx.x;
    if (i < N_EDGES / 2) {
        i32x2 s = __builtin_nontemporal_load(&src2[i]);
        i32x2 d = __builtin_nontemporal_load(&dst2[i]);
        f32x2 wv = __builtin_nontemporal_load(&ew2[i]);
        unsigned p0 = atomicAdd(&cur[d[0]], 1u);
        unsigned p1 = atomicAdd(&cur[d[1]], 1u);
        if (p0 < CAPN) {
            i32x2 m = {s[0], __float_as_int(wv[0])};
            __builtin_nontemporal_store(m, &bkt[(size_t)d[0] * CAPN + p0]);
        }
        if (p1 < CAPN) {
            i32x2 m = {s[1], __float_as_int(wv[1])};
            __builtin_nontemporal_store(m, &bkt[(size_t)d[1] * CAPN + p1]);
        }
    }
}

// ---------------- fused gather-sum + dual GEMM + leaky ----------------
// out = leaky( (dst_x + g) @ Wi^T + (dst_x .* g) @ We^T ),
// g[d] = sum_{e: dst=d} ew_e * src_x[src_e]  (exact f32).
// Gather: each quad (16 lanes) owns 2 whole dst nodes, processed
// SEQUENTIALLY with a 1-deep row prefetch (round-4 structure: VGPR=44,
// no spill, fused=113.5us). Register accumulation only; one plain
// float4 LDS store per row half.
// launch_bounds (256,5): budget 512/5~102 VGPR >> 44 natural -> no
// compression pressure, occupancy 4->5 blocks/CU.
// Lessons: (256,8) and (256,6)+dual-chain both made the allocator
// compress BELOW natural allocation and spill ~100MB (rounds 5,7).
__global__ __launch_bounds__(256, 5) void fused_kernel(
    const float* __restrict__ src_x,
    const float* __restrict__ dst_x,
    const int2* __restrict__ bkt,
    const unsigned* __restrict__ cur,
    const unsigned short* __restrict__ Wfi,
    const unsigned short* __restrict__ Wfe,
    float* __restrict__ out) {
    __shared__ float g[ROWS_PB * GSTR];   // 32 x 132 f32 = 16.9 KB

    int t = threadIdx.x, lane = t & 63, w = t >> 6;
    int quad = lane >> 4, nl = lane & 15;
    int qid = t >> 4;                      // 0..15

    int b = blockIdx.x, d0 = b * ROWS_PB;

    // ---- gather: quad qid owns local rows 2*qid and 2*qid+1 ----
    #pragma unroll
    for (int half = 0; half < 2; ++half) {
        int r = 2 * qid + half;            // local row 0..31
        int node = d0 + r;
        int cn = (int)cur[node];
        if (cn > CAPN) cn = CAPN;
        const int2* bp = bkt + (size_t)node * CAPN;
        float4 a = {0.f, 0.f, 0.f, 0.f}, c = {0.f, 0.f, 0.f, 0.f};
        if (cn > 0) {
            int2 m0 = bp[0];
            const float* p0 = src_x + (size_t)m0.x * D + nl * 8;
            float4 A0 = *(const float4*)p0, B0 = *(const float4*)(p0 + 4);
            for (int e = 0; e < cn; ++e) {
                int en = (e + 1 < cn) ? e + 1 : cn - 1;
                int2 m1 = bp[en];
                const float* p1 = src_x + (size_t)m1.x * D + nl * 8;
                float4 A1 = *(const float4*)p1, B1 = *(const float4*)(p1 + 4);
                float wgt = __int_as_float(m0.y);
                a.x += wgt * A0.x; a.y += wgt * A0.y;
                a.z += wgt * A0.z; a.w += wgt * A0.w;
                c.x += wgt * B0.x; c.y += wgt * B0.y;
                c.z += wgt * B0.z; c.w += wgt * B0.w;
                m0 = m1; A0 = A1; B0 = B1;
            }
        }
        float* gp = &g[r * GSTR + nl * 8];
        *(float4*)gp = a;                  // plain stores: quad owns the row
        *(float4*)(gp + 4) = c;
    }
    __syncthreads();

    // ---- MFMA phase: W fragments (compiler sinks loads here) ----
    const short8* Wiv = (const short8*)Wfi;
    const short8* Wev = (const short8*)Wfe;
    short8 Bi[2][4], Be[2][4];
    #pragma unroll
    for (int ntl = 0; ntl < 2; ++ntl)
        #pragma unroll
        for (int ks = 0; ks < 4; ++ks) {
            Bi[ntl][ks] = Wiv[((2 * w + ntl) * 4 + ks) * 64 + lane];
            Be[ntl][ks] = Wev[((2 * w + ntl) * 4 + ks) * 64 + lane];
        }

    #pragma unroll
    for (int tl = 0; tl < 2; ++tl) {
        int r = tl * 16 + nl;                        // local row 0..31
        const float* xr = dst_x + (size_t)(d0 + r) * D + quad * 8;
        const float* gr = &g[r * GSTR + quad * 8];
        f32x4 acc[2];
        acc[0] = (f32x4){0.f, 0.f, 0.f, 0.f};
        acc[1] = (f32x4){0.f, 0.f, 0.f, 0.f};
        #pragma unroll
        for (int ks = 0; ks < 4; ++ks) {
            float4 f0 = *(const float4*)(xr + ks * 32);
            float4 f1 = *(const float4*)(xr + ks * 32 + 4);
            float4 g0 = *(const float4*)(gr + ks * 32);
            float4 g1 = *(const float4*)(gr + ks * 32 + 4);
            V8 a1v, a2v;
            a1v.u8[0] = f2bf(f0.x + g0.x); a2v.u8[0] = f2bf(f0.x * g0.x);
            a1v.u8[1] = f2bf(f0.y + g0.y); a2v.u8[1] = f2bf(f0.y * g0.y);
            a1v.u8[2] = f2bf(f0.z + g0.z); a2v.u8[2] = f2bf(f0.z * g0.z);
            a1v.u8[3] = f2bf(f0.w + g0.w); a2v.u8[3] = f2bf(f0.w * g0.w);
            a1v.u8[4] = f2bf(f1.x + g1.x); a2v.u8[4] = f2bf(f1.x * g1.x);
            a1v.u8[5] = f2bf(f1.y + g1.y); a2v.u8[5] = f2bf(f1.y * g1.y);
            a1v.u8[6] = f2bf(f1.z + g1.z); a2v.u8[6] = f2bf(f1.z * g1.z);
            a1v.u8[7] = f2bf(f1.w + g1.w); a2v.u8[7] = f2bf(f1.w * g1.w);
            acc[0] = __builtin_amdgcn_mfma_f32_16x16x32_bf16(a1v.s8, Bi[0][ks], acc[0], 0, 0, 0);
            acc[1] = __builtin_amdgcn_mfma_f32_16x16x32_bf16(a1v.s8, Bi[1][ks], acc[1], 0, 0, 0);
            acc[0] = __builtin_amdgcn_mfma_f32_16x16x32_bf16(a2v.s8, Be[0][ks], acc[0], 0, 0, 0);
            acc[1] = __builtin_amdgcn_mfma_f32_16x16x32_bf16(a2v.s8, Be[1][ks], acc[1], 0, 0, 0);
        }
        // store with fused leaky; nontemporal (write-once, keep L2 for gathers)
        #pragma unroll
        for (int ntl = 0; ntl < 2; ++ntl)
            #pragma unroll
            for (int rr = 0; rr < 4; ++rr) {
                float v = acc[ntl][rr];
                v = v > 0.f ? v : 0.01f * v;
                __builtin_nontemporal_store(
                    v, &out[(size_t)(d0 + tl * 16 + quad * 4 + rr) * D
                            + (2 * w + ntl) * 16 + nl]);
            }
    }
}

extern "C" void kernel_launch(void* const* d_in, const int* in_sizes, int n_in,
                              void* d_out, int out_size, void* d_ws, size_t ws_size,
                              hipStream_t stream) {
    const float* src_x = (const float*)d_in[0];
    const float* dst_x = (const float*)d_in[1];
    const int*   eidx  = (const int*)d_in[2];     // [2, E] flat: src then dst
    const float* ew    = (const float*)d_in[3];   // [E, 1]
    const float* Wi    = (const float*)d_in[4];   // [D, D]
    const float* We    = (const float*)d_in[5];   // [D, D]
    float* out = (float*)d_out;

    // ws layout
    char* wsb = (char*)d_ws;
    unsigned short* Wfi = (unsigned short*)(wsb);            // 32768 B
    unsigned short* Wfe = (unsigned short*)(wsb + 32768);    // 32768 B
    unsigned* cur = (unsigned*)(wsb + 65536);                // 400000 B
    int2* bkt = (int2*)(wsb + 65536 + 400000);               // 100000*32*8 = 25.6 MB

    const int* src_idx = eidx;
    const int* dst_idx = eidx + N_EDGES;

    wfrag_kernel<<<64, 256, 0, stream>>>(Wi, We, Wfi, Wfe, cur);

    scatter_kernel<<<(N_EDGES / 2 + 255) / 256, 256, 0, stream>>>(
        (const i32x2*)src_idx, (const i32x2*)dst_idx, (const f32x2*)ew,
        cur, (i32x2*)bkt);

    fused_kernel<<<NBLK_F, 256, 0, stream>>>(
        src_x, dst_x, (const int2*)bkt, cur, Wfi, Wfe, out);
}

// Round 10
// 246.159 us; speedup vs baseline: 1.2086x; 1.1245x over previous
//
#include <hip/hip_runtime.h>
#include <hip/hip_bf16.h>

#define N_NODES 100000
#define N_EDGES 600000
#define D 128
#define ROWS_PB 32                               // dst rows per fused block
#define NBLK_F (N_NODES / ROWS_PB)               // 3125
#define CAPN 32                                  // per-node bucket capacity (mean deg 6, P(>31)~3e-16)
#define GSTR 132                                 // padded LDS row stride (floats)

typedef __attribute__((ext_vector_type(8))) short short8;
typedef __attribute__((ext_vector_type(8))) unsigned short ushort8;
typedef __attribute__((ext_vector_type(4))) float f32x4;
typedef __attribute__((ext_vector_type(2))) int i32x2;
typedef __attribute__((ext_vector_type(2))) float f32x2;

union V8 { short8 s8; ushort8 u8; };

__device__ __forceinline__ unsigned short f2bf(float f) {
    unsigned u = __float_as_uint(f);
    u += 0x7FFF + ((u >> 16) & 1);   // RNE
    return (unsigned short)(u >> 16);
}

// ---------------- weight fragments + per-node cursor zeroing ----------------
// grid = 64 blocks (16384 threads): all clear cur; first 4096 build W frags.
__global__ void wfrag_kernel(const float* __restrict__ Wi,
                             const float* __restrict__ We,
                             unsigned short* __restrict__ Wfi,
                             unsigned short* __restrict__ Wfe,
                             unsigned* __restrict__ cur) {
    int id = blockIdx.x * blockDim.x + threadIdx.x;   // 0..16383
    for (int j = id; j < N_NODES; j += 16384) cur[j] = 0u;   // fold memset in
    if (id >= 4096) return;
    int mat = id >> 11;
    int idx = id & 2047;          // nt<<8 | ks<<6 | lane
    int lane = idx & 63;
    int ks = (idx >> 6) & 3;
    int nt = idx >> 8;
    int n = lane & 15, quad = lane >> 4;
    int row = nt * 16 + n;
    int k0 = ks * 32 + quad * 8;
    const float* W = mat ? We : Wi;
    unsigned short* Wf = mat ? Wfe : Wfi;
    #pragma unroll
    for (int j = 0; j < 8; ++j)
        Wf[idx * 8 + j] = f2bf(W[row * D + k0 + j]);
}

// ---------------- one-pass per-node bucket scatter ----------------
// 2 edges/thread, vector loads, nontemporal (streamed-once) accesses.
// bucket d holds its edges' {src, ew} pairs; within-bucket order irrelevant.
__global__ void scatter_kernel(const i32x2* __restrict__ src2,
                               const i32x2* __restrict__ dst2,
                               const f32x2* __restrict__ ew2,
                               unsigned* __restrict__ cur,
                               i32x2* __restrict__ bkt) {
    int i = blockIdx.x * blockDim.x + threadIdx.x;
    if (i < N_EDGES / 2) {
        i32x2 s = __builtin_nontemporal_load(&src2[i]);
        i32x2 d = __builtin_nontemporal_load(&dst2[i]);
        f32x2 wv = __builtin_nontemporal_load(&ew2[i]);
        unsigned p0 = atomicAdd(&cur[d[0]], 1u);
        unsigned p1 = atomicAdd(&cur[d[1]], 1u);
        if (p0 < CAPN) {
            i32x2 m = {s[0], __float_as_int(wv[0])};
            __builtin_nontemporal_store(m, &bkt[(size_t)d[0] * CAPN + p0]);
        }
        if (p1 < CAPN) {
            i32x2 m = {s[1], __float_as_int(wv[1])};
            __builtin_nontemporal_store(m, &bkt[(size_t)d[1] * CAPN + p1]);
        }
    }
}

// ---------------- fused gather-sum + dual GEMM + leaky ----------------
// out = leaky( (dst_x + g) @ Wi^T + (dst_x .* g) @ We^T ),
// g[d] = sum_{e: dst=d} ew_e * src_x[src_e]  (exact f32).
// Gather: quad owns 2 nodes sequentially (round-4 proven). The node's
// bucket metadata (32 x 8B = one i32x2/lane/half) is preloaded into lane
// registers; slot k's {src,w} comes via __shfl from lane quad*16+(k&15)
// (k is quad-uniform; shfl source is in the reader's own quad -> active).
// The inner loop's ONLY memory op is the row load, prefetched 2-deep
// (A0/A1/A2 rotation) -> no per-edge metadata L2 round-trip on the
// critical path, 2x the row loads in flight.
// launch_bounds (256,4): proven no-spill config (rounds 5/7: tighter
// bounds made the allocator compress below natural and spill ~100MB;
// round 8: a 5th block's permission bought no occupancy anyway).
__global__ __launch_bounds__(256, 4) void fused_kernel(
    const float* __restrict__ src_x,
    const float* __restrict__ dst_x,
    const i32x2* __restrict__ bkt,
    const unsigned* __restrict__ cur,
    const unsigned short* __restrict__ Wfi,
    const unsigned short* __restrict__ Wfe,
    float* __restrict__ out) {
    __shared__ float g[ROWS_PB * GSTR];   // 32 x 132 f32 = 16.9 KB

    int t = threadIdx.x, lane = t & 63, w = t >> 6;
    int quad = lane >> 4, nl = lane & 15;
    int qid = t >> 4;                      // 0..15
    int lbase = (lane >> 4) << 4;          // first lane of this quad

    int b = blockIdx.x, d0 = b * ROWS_PB;

    // ---- gather: quad qid owns local rows 2*qid and 2*qid+1 ----
    #pragma unroll
    for (int half = 0; half < 2; ++half) {
        int r = 2 * qid + half;            // local row 0..31
        int node = d0 + r;
        int cn = (int)cur[node];
        if (cn > CAPN) cn = CAPN;
        const i32x2* bp = bkt + (size_t)node * CAPN;
        // lane-distributed metadata: lane nl holds slots nl and nl+16
        i32x2 mA = __builtin_nontemporal_load(&bp[nl]);
        i32x2 mB = __builtin_nontemporal_load(&bp[nl + 16]);
        float4 a = {0.f, 0.f, 0.f, 0.f}, c = {0.f, 0.f, 0.f, 0.f};
        if (cn > 0) {
            // slots 0,1 are always in mA
            int s0 = __shfl(mA[0], lbase);
            float w0 = __int_as_float(__shfl(mA[1], lbase));
            int i1 = (cn > 1) ? 1 : 0;
            int s1 = __shfl(mA[0], lbase | i1);
            float w1 = __int_as_float(__shfl(mA[1], lbase | i1));
            const float* p0 = src_x + (size_t)s0 * D + nl * 8;
            float4 A0 = *(const float4*)p0, B0 = *(const float4*)(p0 + 4);
            const float* p1 = src_x + (size_t)s1 * D + nl * 8;
            float4 A1 = *(const float4*)p1, B1 = *(const float4*)(p1 + 4);
            for (int e = 0; e < cn; ++e) {
                // issue slot e+2 (clamped); metadata from registers via shfl
                int k = e + 2; if (k > cn - 1) k = cn - 1;
                int srcl = lbase | (k & 15);
                int sk = __shfl(k < 16 ? mA[0] : mB[0], srcl);
                float wk = __int_as_float(__shfl(k < 16 ? mA[1] : mB[1], srcl));
                const float* pk = src_x + (size_t)sk * D + nl * 8;
                float4 A2 = *(const float4*)pk, B2 = *(const float4*)(pk + 4);
                // consume slot e
                a.x += w0 * A0.x; a.y += w0 * A0.y;
                a.z += w0 * A0.z; a.w += w0 * A0.w;
                c.x += w0 * B0.x; c.y += w0 * B0.y;
                c.z += w0 * B0.z; c.w += w0 * B0.w;
                // rotate pipeline
                A0 = A1; B0 = B1; w0 = w1;
                A1 = A2; B1 = B2; w1 = wk;
            }
        }
        float* gp = &g[r * GSTR + nl * 8];
        *(float4*)gp = a;                  // plain stores: quad owns the row
        *(float4*)(gp + 4) = c;
    }
    __syncthreads();

    // ---- MFMA phase: W fragments (compiler sinks loads here) ----
    const short8* Wiv = (const short8*)Wfi;
    const short8* Wev = (const short8*)Wfe;
    short8 Bi[2][4], Be[2][4];
    #pragma unroll
    for (int ntl = 0; ntl < 2; ++ntl)
        #pragma unroll
        for (int ks = 0; ks < 4; ++ks) {
            Bi[ntl][ks] = Wiv[((2 * w + ntl) * 4 + ks) * 64 + lane];
            Be[ntl][ks] = Wev[((2 * w + ntl) * 4 + ks) * 64 + lane];
        }

    #pragma unroll
    for (int tl = 0; tl < 2; ++tl) {
        int r = tl * 16 + nl;                        // local row 0..31
        const float* xr = dst_x + (size_t)(d0 + r) * D + quad * 8;
        const float* gr = &g[r * GSTR + quad * 8];
        f32x4 acc[2];
        acc[0] = (f32x4){0.f, 0.f, 0.f, 0.f};
        acc[1] = (f32x4){0.f, 0.f, 0.f, 0.f};
        #pragma unroll
        for (int ks = 0; ks < 4; ++ks) {
            float4 f0 = *(const float4*)(xr + ks * 32);
            float4 f1 = *(const float4*)(xr + ks * 32 + 4);
            float4 g0 = *(const float4*)(gr + ks * 32);
            float4 g1 = *(const float4*)(gr + ks * 32 + 4);
            V8 a1v, a2v;
            a1v.u8[0] = f2bf(f0.x + g0.x); a2v.u8[0] = f2bf(f0.x * g0.x);
            a1v.u8[1] = f2bf(f0.y + g0.y); a2v.u8[1] = f2bf(f0.y * g0.y);
            a1v.u8[2] = f2bf(f0.z + g0.z); a2v.u8[2] = f2bf(f0.z * g0.z);
            a1v.u8[3] = f2bf(f0.w + g0.w); a2v.u8[3] = f2bf(f0.w * g0.w);
            a1v.u8[4] = f2bf(f1.x + g1.x); a2v.u8[4] = f2bf(f1.x * g1.x);
            a1v.u8[5] = f2bf(f1.y + g1.y); a2v.u8[5] = f2bf(f1.y * g1.y);
            a1v.u8[6] = f2bf(f1.z + g1.z); a2v.u8[6] = f2bf(f1.z * g1.z);
            a1v.u8[7] = f2bf(f1.w + g1.w); a2v.u8[7] = f2bf(f1.w * g1.w);
            acc[0] = __builtin_amdgcn_mfma_f32_16x16x32_bf16(a1v.s8, Bi[0][ks], acc[0], 0, 0, 0);
            acc[1] = __builtin_amdgcn_mfma_f32_16x16x32_bf16(a1v.s8, Bi[1][ks], acc[1], 0, 0, 0);
            acc[0] = __builtin_amdgcn_mfma_f32_16x16x32_bf16(a2v.s8, Be[0][ks], acc[0], 0, 0, 0);
            acc[1] = __builtin_amdgcn_mfma_f32_16x16x32_bf16(a2v.s8, Be[1][ks], acc[1], 0, 0, 0);
        }
        // store with fused leaky; plain stores (NT cost +15MB WRITE in r8)
        #pragma unroll
        for (int ntl = 0; ntl < 2; ++ntl)
            #pragma unroll
            for (int rr = 0; rr < 4; ++rr) {
                float v = acc[ntl][rr];
                v = v > 0.f ? v : 0.01f * v;
                out[(size_t)(d0 + tl * 16 + quad * 4 + rr) * D
                    + (2 * w + ntl) * 16 + nl] = v;
            }
    }
}

extern "C" void kernel_launch(void* const* d_in, const int* in_sizes, int n_in,
                              void* d_out, int out_size, void* d_ws, size_t ws_size,
                              hipStream_t stream) {
    const float* src_x = (const float*)d_in[0];
    const float* dst_x = (const float*)d_in[1];
    const int*   eidx  = (const int*)d_in[2];     // [2, E] flat: src then dst
    const float* ew    = (const float*)d_in[3];   // [E, 1]
    const float* Wi    = (const float*)d_in[4];   // [D, D]
    const float* We    = (const float*)d_in[5];   // [D, D]
    float* out = (float*)d_out;

    // ws layout
    char* wsb = (char*)d_ws;
    unsigned short* Wfi = (unsigned short*)(wsb);            // 32768 B
    unsigned short* Wfe = (unsigned short*)(wsb + 32768);    // 32768 B
    unsigned* cur = (unsigned*)(wsb + 65536);                // 400000 B
    i32x2* bkt = (i32x2*)(wsb + 65536 + 400000);             // 100000*32*8 = 25.6 MB

    const int* src_idx = eidx;
    const int* dst_idx = eidx + N_EDGES;

    wfrag_kernel<<<64, 256, 0, stream>>>(Wi, We, Wfi, Wfe, cur);

    scatter_kernel<<<(N_EDGES / 2 + 255) / 256, 256, 0, stream>>>(
        (const i32x2*)src_idx, (const i32x2*)dst_idx, (const f32x2*)ew,
        cur, bkt);

    fused_kernel<<<NBLK_F, 256, 0, stream>>>(
        src_x, dst_x, bkt, cur, Wfi, Wfe, out);
}